// Round 1
// baseline (331.916 us; speedup 1.0000x reference)
//
#include <hip/hip_runtime.h>

// SimpleSNN: T=16, B=4096, N_IN=784, N_HID=256, N_OUT=10
// Phase 1: C1[m][n] = b1[n] + sum_k X[m][k]*W1[n][k]   (m = t*B+b, M=65536)
// Phase 2: LIF1 recurrence over t per (b,n); z1 overwrites C1 in place
// Phase 3: C2[m][o] = b2[o] + sum_n z1[m][n]*W2[o][n]
// Phase 4: LIF2 recurrence over t per (b,o); out[b][o] = sum_t z2

#define T_STEPS 16
#define B_SZ    4096
#define N_IN    784
#define N_HID   256
#define N_OUT   10
#define M_TOT   (T_STEPS * B_SZ)   // 65536

// ---------------- GEMM1: fp32, 128x128 tile, BK=16, 256 thr, 8x8 micro ----
__global__ __launch_bounds__(256) void gemm1_f32(
    const float* __restrict__ X, const float* __restrict__ W,
    const float* __restrict__ bias, float* __restrict__ C)
{
    // K-major staging transposed to [k][row] so fragments read as float4
    __shared__ float Xs[16][132];   // pad 132: stride 528B = 33*16 -> aligned float4
    __shared__ float Ws[16][132];

    const int tid = threadIdx.x;
    const int tx = tid & 15, ty = tid >> 4;
    const int m0 = blockIdx.x * 128;
    const int n0 = blockIdx.y * 128;

    float acc[8][8] = {};

    for (int k0 = 0; k0 < N_IN; k0 += 16) {
        #pragma unroll
        for (int l = 0; l < 2; ++l) {
            const int idx = tid + l * 256;      // 0..511
            const int row = idx >> 2;           // 0..127
            const int kq  = (idx & 3) << 2;     // 0,4,8,12
            const float4 xv = *reinterpret_cast<const float4*>(
                X + (size_t)(m0 + row) * N_IN + k0 + kq);
            Xs[kq + 0][row] = xv.x; Xs[kq + 1][row] = xv.y;
            Xs[kq + 2][row] = xv.z; Xs[kq + 3][row] = xv.w;
            const float4 wv = *reinterpret_cast<const float4*>(
                W + (size_t)(n0 + row) * N_IN + k0 + kq);
            Ws[kq + 0][row] = wv.x; Ws[kq + 1][row] = wv.y;
            Ws[kq + 2][row] = wv.z; Ws[kq + 3][row] = wv.w;
        }
        __syncthreads();

        #pragma unroll
        for (int kk = 0; kk < 16; ++kk) {
            float a[8], b[8];
            *(float4*)&a[0] = *(const float4*)&Xs[kk][ty * 8];
            *(float4*)&a[4] = *(const float4*)&Xs[kk][ty * 8 + 4];
            *(float4*)&b[0] = *(const float4*)&Ws[kk][tx * 8];
            *(float4*)&b[4] = *(const float4*)&Ws[kk][tx * 8 + 4];
            #pragma unroll
            for (int i = 0; i < 8; ++i)
                #pragma unroll
                for (int j = 0; j < 8; ++j)
                    acc[i][j] = fmaf(a[i], b[j], acc[i][j]);
        }
        __syncthreads();
    }

    #pragma unroll
    for (int i = 0; i < 8; ++i) {
        const size_t m = (size_t)(m0 + ty * 8 + i);
        #pragma unroll
        for (int j = 0; j < 8; j += 4) {
            const int n = n0 + tx * 8 + j;
            float4 o;
            o.x = acc[i][j + 0] + bias[n + 0];
            o.y = acc[i][j + 1] + bias[n + 1];
            o.z = acc[i][j + 2] + bias[n + 2];
            o.w = acc[i][j + 3] + bias[n + 3];
            *reinterpret_cast<float4*>(C + m * N_HID + n) = o;
        }
    }
}

// ---------------- LIF1: per (b,n), loop t; overwrite C1 with z1 ------------
__global__ __launch_bounds__(256) void lif1_kernel(float* __restrict__ C1)
{
    const int g = blockIdx.x * 256 + threadIdx.x;   // b*256+n, < B*N_HID
    const size_t stride = (size_t)B_SZ * N_HID;
    float v = 0.0f, cur = 0.0f;
    #pragma unroll
    for (int t = 0; t < T_STEPS; ++t) {
        const size_t off = (size_t)t * stride + g;
        const float c = C1[off];
        const float vd = v + 0.1f * ((0.0f - v) + cur);
        const float id = cur - 0.2f * cur;
        const bool  sp = vd > 1.0f;
        C1[off] = sp ? 1.0f : 0.0f;
        v = sp ? 0.0f : vd;
        cur = id + c;
    }
}

// ---------------- GEMM2: M=65536, K=256, N=10; 64 rows/block, 640 thr ------
__global__ __launch_bounds__(640) void gemm2_f32(
    const float* __restrict__ Z, const float* __restrict__ W2,
    const float* __restrict__ b2, float* __restrict__ C2)
{
    __shared__ float zs[64 * 268];  // stride 268: 16B-aligned, %32==12 (bank spread)
    __shared__ float ws[N_OUT * N_HID];
    const int tid = threadIdx.x;
    const int m0 = blockIdx.x * 64;

    for (int idx = tid; idx < 4096; idx += 640) {     // 64x256 floats as float4
        const int r = idx >> 6;
        const int c = (idx & 63) << 2;
        *(float4*)&zs[r * 268 + c] =
            *(const float4*)&Z[(size_t)(m0 + r) * N_HID + c];
    }
    *(float4*)&ws[tid * 4] = *(const float4*)&W2[tid * 4];  // 640*4 = 2560 exactly
    __syncthreads();

    const int o = tid >> 6;       // 0..9 (one wave per output)
    const int r = tid & 63;       // row within tile
    float acc = b2[o];
    #pragma unroll
    for (int k = 0; k < N_HID; k += 4) {
        const float4 z4 = *(const float4*)&zs[r * 268 + k];
        const float4 w4 = *(const float4*)&ws[o * N_HID + k];
        acc += z4.x * w4.x + z4.y * w4.y + z4.z * w4.z + z4.w * w4.w;
    }
    C2[(size_t)(m0 + r) * N_OUT + o] = acc;
}

// ---------------- LIF2: per (b,o), loop t; accumulate spike count ----------
__global__ __launch_bounds__(256) void lif2_kernel(
    const float* __restrict__ C2, float* __restrict__ out)
{
    const int g = blockIdx.x * 256 + threadIdx.x;   // b*10+o, < 40960
    const int stride = B_SZ * N_OUT;
    float v = 0.0f, cur = 0.0f, s = 0.0f;
    #pragma unroll
    for (int t = 0; t < T_STEPS; ++t) {
        const float c = C2[t * stride + g];
        const float vd = v + 0.1f * ((0.0f - v) + cur);
        const float id = cur - 0.2f * cur;
        const bool  sp = vd > 1.0f;
        s += sp ? 1.0f : 0.0f;
        v = sp ? 0.0f : vd;
        cur = id + c;
    }
    out[g] = s;
}

extern "C" void kernel_launch(void* const* d_in, const int* in_sizes, int n_in,
                              void* d_out, int out_size, void* d_ws, size_t ws_size,
                              hipStream_t stream)
{
    const float* X  = (const float*)d_in[0];   // (T,B,784) binary spikes
    const float* W1 = (const float*)d_in[1];   // (256,784)
    const float* b1 = (const float*)d_in[2];   // (256)
    const float* W2 = (const float*)d_in[3];   // (10,256)
    const float* b2 = (const float*)d_in[4];   // (10)
    float* out = (float*)d_out;                // (4096,10)

    float* C1 = (float*)d_ws;                    // 65536 x 256 fp32 = 67 MB (reused as z1)
    float* C2 = C1 + (size_t)M_TOT * N_HID;      // 65536 x 10 fp32 = 2.6 MB

    dim3 g1(M_TOT / 128, N_HID / 128);           // (512, 2)
    gemm1_f32<<<g1, 256, 0, stream>>>(X, W1, b1, C1);

    lif1_kernel<<<(B_SZ * N_HID) / 256, 256, 0, stream>>>(C1);

    gemm2_f32<<<M_TOT / 64, 640, 0, stream>>>(C1, W2, b2, C2);

    lif2_kernel<<<(B_SZ * N_OUT) / 256, 256, 0, stream>>>(C2, out);
}

// Round 2
// 132.086 us; speedup vs baseline: 2.5129x; 2.5129x over previous
//
#include <hip/hip_runtime.h>

// SimpleSNN: T=16, B=4096, N_IN=784, N_HID=256, N_OUT=10
// Pipeline:
//   conv_w     : W1 -> W_hi/W_lo bf16 (RNE split), K padded 784->800
//   gemm1_mfma : C1[m][n] = b1[n] + sum_k X[m][k]*W1[n][k], m = t*B+b (M=65536)
//                X staged fp32->bf16 in-kernel (exact for {0,1}); two MFMA
//                accumulations (hi+lo) recover fp32-class precision.
//   lif1       : LIF recurrence over t per (b,n); z1 overwrites C1 in place
//   gemm2_f32  : C2 = z1 @ W2.T + b2
//   lif2       : LIF recurrence + spike count -> out

#define T_STEPS 16
#define B_SZ    4096
#define N_IN    784
#define N_HID   256
#define N_OUT   10
#define M_TOT   (T_STEPS * B_SZ)   // 65536
#define KPAD    800                // 784 padded to 25*32

typedef __bf16 bf16x8 __attribute__((ext_vector_type(8)));
typedef float  f32x4  __attribute__((ext_vector_type(4)));
typedef unsigned short ushort_t;

// ---------------- conv_w: split W1 into hi/lo bf16, pad K to 800 -----------
__device__ __forceinline__ unsigned short bf16_rne(float f) {
    unsigned u = __builtin_bit_cast(unsigned, f);
    u += 0x7fffu + ((u >> 16) & 1u);
    return (unsigned short)(u >> 16);
}

__global__ __launch_bounds__(256) void conv_w(
    const float* __restrict__ W1,
    unsigned short* __restrict__ Whi, unsigned short* __restrict__ Wlo)
{
    const int idx = blockIdx.x * 256 + threadIdx.x;   // over 256*800
    if (idx >= N_HID * KPAD) return;
    const int n = idx / KPAD, k = idx % KPAD;
    unsigned short h = 0, l = 0;
    if (k < N_IN) {
        const float w = W1[n * N_IN + k];
        h = bf16_rne(w);
        const float hf = __builtin_bit_cast(float, (unsigned)h << 16);
        l = bf16_rne(w - hf);
    }
    Whi[idx] = h;
    Wlo[idx] = l;
}

// ---------------- gemm1: MFMA bf16 split, 128x256 tile, BK=32, 512 thr -----
__global__ __launch_bounds__(512, 4) void gemm1_mfma(
    const float* __restrict__ X,
    const unsigned short* __restrict__ Whi,
    const unsigned short* __restrict__ Wlo,
    const float* __restrict__ b1,
    float* __restrict__ C)
{
    // LDS: A 128x32 bf16 (8KB), Bhi/Blo 256x32 bf16 (16KB each), double-buffered
    __shared__ ushort_t As[2][128 * 32];
    __shared__ ushort_t Bh[2][256 * 32];
    __shared__ ushort_t Bl[2][256 * 32];

    const int tid  = threadIdx.x;
    const int lane = tid & 63;
    const int w    = tid >> 6;          // wave 0..7
    const int wm   = w >> 2;            // 0..1  (m sub-tile)
    const int wn   = w & 3;             // 0..3  (n sub-tile)
    const int m0   = blockIdx.x * 128;

    // A staging (reg path): thread -> (row ar, phys slot ap); source slot XOR-swizzled
    const int ar  = tid >> 2;           // 0..127
    const int ap  = tid & 3;
    const int acs = ap ^ (ar & 3);      // global k16-slot feeding phys slot ap
    const float* aSrc = X + (size_t)(m0 + ar) * N_IN + acs * 8;

    f32x4 acc[4][4];
    #pragma unroll
    for (int i = 0; i < 4; ++i)
        #pragma unroll
        for (int j = 0; j < 4; ++j)
            #pragma unroll
            for (int q = 0; q < 4; ++q)
                acc[i][j][q] = 0.0f;

    auto stage = [&](int bi, int kt) {
        const int k0 = kt * 32;
        // B tiles via global_load_lds (dest linear; source pre-swizzled).
        // wave w stages rows [w*32, w*32+32) of both Bhi and Blo; 1KB per issue.
        #pragma unroll
        for (int ii = 0; ii < 2; ++ii) {
            const int rb = w * 32 + ii * 16 + (lane >> 2);
            const int cs = (lane & 3) ^ (rb & 3);
            const size_t go = (size_t)rb * KPAD + k0 + cs * 8;
            ushort_t* dh = &Bh[bi][(w * 32 + ii * 16) * 32];
            ushort_t* dl = &Bl[bi][(w * 32 + ii * 16) * 32];
            __builtin_amdgcn_global_load_lds(
                (const __attribute__((address_space(1))) void*)(Whi + go),
                (__attribute__((address_space(3))) void*)dh, 16, 0, 0);
            __builtin_amdgcn_global_load_lds(
                (const __attribute__((address_space(1))) void*)(Wlo + go),
                (__attribute__((address_space(3))) void*)dl, 16, 0, 0);
        }
        // A tile: fp32 load + truncate-pack to bf16 (exact for {0,1}), ds_write_b128
        const int kg = k0 + acs * 8;
        uint4 pk = make_uint4(0u, 0u, 0u, 0u);
        if (kg < N_IN) {
            const float4* s = reinterpret_cast<const float4*>(aSrc + k0);
            const float4 f0 = s[0];
            const float4 f1 = s[1];
            pk.x = (__builtin_bit_cast(unsigned, f0.x) >> 16) |
                   (__builtin_bit_cast(unsigned, f0.y) & 0xffff0000u);
            pk.y = (__builtin_bit_cast(unsigned, f0.z) >> 16) |
                   (__builtin_bit_cast(unsigned, f0.w) & 0xffff0000u);
            pk.z = (__builtin_bit_cast(unsigned, f1.x) >> 16) |
                   (__builtin_bit_cast(unsigned, f1.y) & 0xffff0000u);
            pk.w = (__builtin_bit_cast(unsigned, f1.z) >> 16) |
                   (__builtin_bit_cast(unsigned, f1.w) & 0xffff0000u);
        }
        *reinterpret_cast<uint4*>(&As[bi][ar * 32 + ap * 8]) = pk;
    };

    const int NT = KPAD / 32;   // 25
    int buf = 0;
    stage(0, 0);

    for (int kt = 0; kt < NT; ++kt) {
        __syncthreads();        // drains vmcnt+lgkmcnt: staged buf ready, prior reads done

        // fragment reads for this buffer (A + B_hi first; B_lo after hi-MFMAs)
        bf16x8 af[4];
        #pragma unroll
        for (int i = 0; i < 4; ++i) {
            const int r = wm * 64 + i * 16 + (lane & 15);
            const int p = (lane >> 4) ^ (r & 3);
            af[i] = *reinterpret_cast<const bf16x8*>(&As[buf][r * 32 + p * 8]);
        }
        bf16x8 bfr[4];
        #pragma unroll
        for (int j = 0; j < 4; ++j) {
            const int r = wn * 64 + j * 16 + (lane & 15);
            const int p = (lane >> 4) ^ (r & 3);
            bfr[j] = *reinterpret_cast<const bf16x8*>(&Bh[buf][r * 32 + p * 8]);
        }

        if (kt + 1 < NT) stage(buf ^ 1, kt + 1);   // prefetch next tile

        #pragma unroll
        for (int i = 0; i < 4; ++i)
            #pragma unroll
            for (int j = 0; j < 4; ++j)
                acc[i][j] = __builtin_amdgcn_mfma_f32_16x16x32_bf16(
                    af[i], bfr[j], acc[i][j], 0, 0, 0);

        #pragma unroll
        for (int j = 0; j < 4; ++j) {
            const int r = wn * 64 + j * 16 + (lane & 15);
            const int p = (lane >> 4) ^ (r & 3);
            bfr[j] = *reinterpret_cast<const bf16x8*>(&Bl[buf][r * 32 + p * 8]);
        }
        #pragma unroll
        for (int i = 0; i < 4; ++i)
            #pragma unroll
            for (int j = 0; j < 4; ++j)
                acc[i][j] = __builtin_amdgcn_mfma_f32_16x16x32_bf16(
                    af[i], bfr[j], acc[i][j], 0, 0, 0);

        buf ^= 1;
    }

    // epilogue: C/D layout col=lane&15, row=(lane>>4)*4+q  (m89-verified)
    #pragma unroll
    for (int j = 0; j < 4; ++j) {
        const int col  = wn * 64 + j * 16 + (lane & 15);
        const float bb = b1[col];
        #pragma unroll
        for (int i = 0; i < 4; ++i) {
            const int rbase = m0 + wm * 64 + i * 16 + ((lane >> 4) << 2);
            #pragma unroll
            for (int q = 0; q < 4; ++q)
                C[(size_t)(rbase + q) * N_HID + col] = acc[i][j][q] + bb;
        }
    }
}

// ---------------- LIF1: per (b,n), loop t; overwrite C1 with z1 ------------
__global__ __launch_bounds__(256) void lif1_kernel(float* __restrict__ C1)
{
    const int g = blockIdx.x * 256 + threadIdx.x;   // b*256+n, < B*N_HID
    const size_t stride = (size_t)B_SZ * N_HID;
    float v = 0.0f, cur = 0.0f;
    #pragma unroll
    for (int t = 0; t < T_STEPS; ++t) {
        const size_t off = (size_t)t * stride + g;
        const float c = C1[off];
        const float vd = v + 0.1f * ((0.0f - v) + cur);
        const float id = cur - 0.2f * cur;
        const bool  sp = vd > 1.0f;
        C1[off] = sp ? 1.0f : 0.0f;
        v = sp ? 0.0f : vd;
        cur = id + c;
    }
}

// ---------------- GEMM2: M=65536, K=256, N=10; 64 rows/block, 640 thr ------
__global__ __launch_bounds__(640) void gemm2_f32(
    const float* __restrict__ Z, const float* __restrict__ W2,
    const float* __restrict__ b2, float* __restrict__ C2)
{
    __shared__ float zs[64 * 268];  // stride 268: 16B-aligned, %32==12 (bank spread)
    __shared__ float ws[N_OUT * N_HID];
    const int tid = threadIdx.x;
    const int m0 = blockIdx.x * 64;

    for (int idx = tid; idx < 4096; idx += 640) {     // 64x256 floats as float4
        const int r = idx >> 6;
        const int c = (idx & 63) << 2;
        *(float4*)&zs[r * 268 + c] =
            *(const float4*)&Z[(size_t)(m0 + r) * N_HID + c];
    }
    *(float4*)&ws[tid * 4] = *(const float4*)&W2[tid * 4];  // 640*4 = 2560 exactly
    __syncthreads();

    const int o = tid >> 6;       // 0..9 (one wave per output)
    const int r = tid & 63;       // row within tile
    float acc = b2[o];
    #pragma unroll
    for (int k = 0; k < N_HID; k += 4) {
        const float4 z4 = *(const float4*)&zs[r * 268 + k];
        const float4 w4 = *(const float4*)&ws[o * N_HID + k];
        acc += z4.x * w4.x + z4.y * w4.y + z4.z * w4.z + z4.w * w4.w;
    }
    C2[(size_t)(m0 + r) * N_OUT + o] = acc;
}

// ---------------- LIF2: per (b,o), loop t; accumulate spike count ----------
__global__ __launch_bounds__(256) void lif2_kernel(
    const float* __restrict__ C2, float* __restrict__ out)
{
    const int g = blockIdx.x * 256 + threadIdx.x;   // b*10+o, < 40960
    const int stride = B_SZ * N_OUT;
    float v = 0.0f, cur = 0.0f, s = 0.0f;
    #pragma unroll
    for (int t = 0; t < T_STEPS; ++t) {
        const float c = C2[t * stride + g];
        const float vd = v + 0.1f * ((0.0f - v) + cur);
        const float id = cur - 0.2f * cur;
        const bool  sp = vd > 1.0f;
        s += sp ? 1.0f : 0.0f;
        v = sp ? 0.0f : vd;
        cur = id + c;
    }
    out[g] = s;
}

extern "C" void kernel_launch(void* const* d_in, const int* in_sizes, int n_in,
                              void* d_out, int out_size, void* d_ws, size_t ws_size,
                              hipStream_t stream)
{
    const float* X  = (const float*)d_in[0];   // (T,B,784) binary spikes
    const float* W1 = (const float*)d_in[1];   // (256,784)
    const float* b1 = (const float*)d_in[2];   // (256)
    const float* W2 = (const float*)d_in[3];   // (10,256)
    const float* b2 = (const float*)d_in[4];   // (10)
    float* out = (float*)d_out;                // (4096,10)

    unsigned short* Whi = (unsigned short*)d_ws;           // 256*800 bf16
    unsigned short* Wlo = Whi + N_HID * KPAD;              // 256*800 bf16
    float* C1 = (float*)((char*)d_ws + (1 << 20));         // 65536x256 fp32 (reused as z1)
    float* C2 = C1 + (size_t)M_TOT * N_HID;                // 65536x10 fp32

    conv_w<<<(N_HID * KPAD + 255) / 256, 256, 0, stream>>>(W1, Whi, Wlo);

    gemm1_mfma<<<M_TOT / 128, 512, 0, stream>>>(X, Whi, Wlo, b1, C1);

    lif1_kernel<<<(B_SZ * N_HID) / 256, 256, 0, stream>>>(C1);

    gemm2_f32<<<M_TOT / 64, 640, 0, stream>>>(C1, W2, b2, C2);

    lif2_kernel<<<(B_SZ * N_OUT) / 256, 256, 0, stream>>>(C2, out);
}